// Round 4
// baseline (755.005 us; speedup 1.0000x reference)
//
#include <hip/hip_runtime.h>
#include <math.h>

// ---------- Problem constants ----------
#define N_NODES 65536
#define B_GR    8
#define EMB_N   512
#define E_EDGES 458752     // N * 7
#define NSEG    458752     // N * 7 segments (row*7 + etype)
#define TSTRIDE 288        // per-type padded K (263 used: 256 feat + 7 onehot)
#define GK      2016       // 7 * 288 (fallback fused-B layout)
#define YSTR    296        // y row stride u16 (288 data + 8 pad; 148 dwords -> 2-way banks)
#define ZN      1792       // z row width (7 types x 256)
#define EPS     1e-5f

typedef unsigned short u16;
typedef unsigned int   u32;
typedef __bf16 bf16x8 __attribute__((ext_vector_type(8)));
typedef float  f32x4  __attribute__((ext_vector_type(4)));
typedef u16    u16x8  __attribute__((ext_vector_type(8)));

__device__ __forceinline__ float bf2f(u16 u) {
    u32 x = ((u32)u) << 16; float f; __builtin_memcpy(&f, &x, 4); return f;
}
__device__ __forceinline__ u16 f2bf(float f) {
    u32 x; __builtin_memcpy(&x, &f, 4);
    u32 r = x + 0x7fffu + ((x >> 16) & 1u);
    return (u16)(r >> 16);
}
__device__ __forceinline__ void gload16(const u16* g, u16* l) {
    __builtin_amdgcn_global_load_lds((const __attribute__((address_space(1))) void*)g,
                                     (__attribute__((address_space(3))) void*)l, 16, 0, 0);
}

// ---------- shared device bodies ----------
__device__ __forceinline__ void stats_body(int nb, int tid, const float* __restrict__ xin,
                                           const int* __restrict__ batch_id,
                                           float* __restrict__ S, float* __restrict__ Q) {
    int c = tid;
    int n0 = nb * 64;
    float s = 0.f, q = 0.f;
    int bcur = batch_id[n0];
    for (int r = 0; r < 64; r++) {
        int n = n0 + r;
        int b = batch_id[n];
        if (b != bcur) {
            atomicAdd(&S[bcur * 256 + c], s);
            atomicAdd(&Q[bcur * 256 + c], q);
            s = 0.f; q = 0.f; bcur = b;
        }
        float v = xin[(size_t)n * 256 + c];
        s += v;
        q = fmaf(v, v, q);
    }
    atomicAdd(&S[bcur * 256 + c], s);
    atomicAdd(&Q[bcur * 256 + c], q);
}

// norm + affine + SiLU with inline group-stat finalize; writes y stride 296
// cols 0..255 = silu(gn(x)); 256..262 = onehot(node_type); 263..287 = 0.
__device__ __forceinline__ void norm_body(int nb, int tid, const float* __restrict__ xin,
                                          const int* __restrict__ batch_id,
                                          const float* __restrict__ S, const float* __restrict__ Q,
                                          const int* __restrict__ cnt,
                                          const float* __restrict__ w, const float* __restrict__ bias,
                                          const int* __restrict__ node_type,
                                          u16* __restrict__ yout) {
    __shared__ float smean[256], sistd[256];
    {
        int b = tid >> 5, g = tid & 31;
        float Sg = 0.f, Qg = 0.f;
#pragma unroll
        for (int k = 0; k < 8; k++) {
            Sg += S[b * 256 + g * 8 + k];
            Qg += Q[b * 256 + g * 8 + k];
        }
        float cnt8 = (float)cnt[b] * 8.f;
        float D = cnt8 + EPS;                  // matches reference: count*cpg + EPS
        float m = Sg / D;
        float var = (Qg - 2.f * m * Sg + cnt8 * m * m) / D;
        smean[tid] = m;
        sistd[tid] = rsqrtf(var + EPS);
    }
    __syncthreads();
    int n = nb * 8 + (tid >> 5);
    int g = tid & 31;
    int c0 = g * 8;
    int b = batch_id[n];
    float m = smean[b * 32 + g], is = sistd[b * 32 + g];
    u16x8 o;
#pragma unroll
    for (int k = 0; k < 8; k++) {
        float v = (xin[(size_t)n * 256 + c0 + k] - m) * is;
        v = v * w[c0 + k] + bias[c0 + k];
        v = v / (1.f + __expf(-v));
        o[k] = f2bf(v);
    }
    *(u16x8*)&yout[(size_t)n * YSTR + c0] = o;
    if (g < 4) {                    // append onehot + zero-pad octets (cols 256..287)
        u16x8 oh;
#pragma unroll
        for (int k = 0; k < 8; k++) oh[k] = 0;
        if (g == 0) {
            int nt = node_type[n];
#pragma unroll
            for (int k = 0; k < 7; k++) oh[k] = (nt == k) ? (u16)0x3F80 : (u16)0;
        }
        *(u16x8*)&yout[(size_t)n * YSTR + 256 + g * 8] = oh;
    }
}

// ---------- K1: count + weight transpose + emb GEMM + stats1 (fused front) ----------
// zmode=1: Wt[(t*256+n)*288 + c]  (z-GEMM B layout)
// zmode=0: Wt[n*2016 + t*288 + c] (fused fallback B layout)
__global__ __launch_bounds__(256) void front_kernel(
    const int* __restrict__ batch_id, int* __restrict__ cnt,
    const float* __restrict__ w1, const float* __restrict__ w2,
    u16* __restrict__ Wt1, u16* __restrict__ Wt2,
    const float* __restrict__ emb, const float* __restrict__ embw,
    const float* __restrict__ embb, float* __restrict__ embout,
    const float* __restrict__ x, float* __restrict__ S, float* __restrict__ Q, int zmode)
{
    int bid = blockIdx.x, tid = threadIdx.x;
    if (bid < 256) {
        int i = bid * 256 + tid;
        int b = batch_id[i];
#pragma unroll
        for (int bb = 0; bb < 8; bb++) {
            unsigned long long mm = __ballot(b == bb);
            if ((tid & 63) == 0 && mm) atomicAdd(&cnt[bb], (int)__popcll(mm));
        }
    } else if (bid < 1264) {
        // weight transpose+pad (f32 -> bf16), 32x32 LDS tiles, coalesced both sides
        int r = bid - 256;
        const float* Win = (r < 504) ? w1 : w2;
        u16* Wt = (r < 504) ? Wt1 : Wt2;
        r %= 504;
        int t  = r / 72;
        int r2 = r % 72;
        int cc0 = (r2 / 8) * 32;       // 9 c-tiles cover padded 0..287
        int n0  = (r2 % 8) * 32;
        __shared__ float tile[32][33];
        int cl = tid & 31, rh = tid >> 5;
#pragma unroll
        for (int rr = 0; rr < 4; rr++) {
            int c = cc0 + rh + rr * 8;
            float v = 0.f;
            if (c < 263) v = Win[(size_t)(t * 263 + c) * 256 + n0 + cl];
            tile[rh + rr * 8][cl] = v;
        }
        __syncthreads();
#pragma unroll
        for (int rr = 0; rr < 4; rr++) {
            int n = n0 + rh + rr * 8;
            u16 v = f2bf(tile[cl][rh + rr * 8]);
            if (zmode)
                Wt[(size_t)(t * 256 + n) * 288 + cc0 + cl] = v;
            else
                Wt[(size_t)n * GK + t * TSTRIDE + cc0 + cl] = v;
        }
    } else if (bid == 1264) {
        __shared__ float semb[B_GR * EMB_N];
        for (int i = tid; i < B_GR * EMB_N; i += 256) {
            float e = emb[i];
            semb[i] = e / (1.f + __expf(-e));
        }
        __syncthreads();
        float acc[8];
        float bb = embb[tid];
#pragma unroll
        for (int b = 0; b < 8; b++) acc[b] = bb;
        for (int k = 0; k < EMB_N; k++) {
            float wv = embw[k * 256 + tid];
#pragma unroll
            for (int b = 0; b < 8; b++) acc[b] += semb[b * EMB_N + k] * wv;
        }
#pragma unroll
        for (int b = 0; b < 8; b++) embout[b * 256 + tid] = acc[b];
    } else {
        stats_body(bid - 1265, tid, x, batch_id, S, Q);
    }
}

// ---------- K2: hist + norm1 (fused) ----------
__global__ __launch_bounds__(256) void hist_norm_kernel(
    const int* __restrict__ ei, const int* __restrict__ et, int* __restrict__ hist,
    const float* __restrict__ xin, const int* __restrict__ batch_id,
    const float* __restrict__ S, const float* __restrict__ Q, const int* __restrict__ cnt,
    const float* __restrict__ w, const float* __restrict__ bias,
    const int* __restrict__ node_type, u16* __restrict__ yout)
{
    int bid = blockIdx.x;
    if (bid < 1792) {
        int e = bid * 256 + threadIdx.x;   // 1792*256 == E_EDGES exactly
        int s = ei[e] * 7 + et[e];
        atomicAdd(&hist[s], 1);
    } else {
        norm_body(bid - 1792, threadIdx.x, xin, batch_id, S, Q, cnt, w, bias, node_type, yout);
    }
}

// ---------- standalone stats2 / norm2 ----------
__global__ __launch_bounds__(256) void stats_kernel(const float* __restrict__ xin,
                                                    const int* __restrict__ batch_id,
                                                    float* __restrict__ S, float* __restrict__ Q) {
    stats_body(blockIdx.x, threadIdx.x, xin, batch_id, S, Q);
}
__global__ __launch_bounds__(256) void norm_kernel(const float* __restrict__ xin,
                                                   const int* __restrict__ batch_id,
                                                   const float* __restrict__ S, const float* __restrict__ Q,
                                                   const int* __restrict__ cnt,
                                                   const float* __restrict__ w, const float* __restrict__ bias,
                                                   const int* __restrict__ node_type,
                                                   u16* __restrict__ yout) {
    norm_body(blockIdx.x, threadIdx.x, xin, batch_id, S, Q, cnt, w, bias, node_type, yout);
}

// ---------- CSR scans ----------
__global__ __launch_bounds__(512) void scan1_kernel(const int* __restrict__ hist, int* __restrict__ partials) {
    __shared__ int sd[512];
    int i = blockIdx.x * 512 + threadIdx.x;
    sd[threadIdx.x] = hist[i];
    __syncthreads();
    for (int off = 256; off > 0; off >>= 1) {
        if (threadIdx.x < off) sd[threadIdx.x] += sd[threadIdx.x + off];
        __syncthreads();
    }
    if (threadIdx.x == 0) partials[blockIdx.x] = sd[0];
}

__global__ __launch_bounds__(1024) void scan2_kernel(int* __restrict__ partials) {
    __shared__ int sd[1024];
    int t = threadIdx.x;
    int v = (t < 896) ? partials[t] : 0;
    sd[t] = v;
    __syncthreads();
    for (int off = 1; off < 1024; off <<= 1) {
        int u = (t >= off) ? sd[t - off] : 0;
        __syncthreads();
        sd[t] += u;
        __syncthreads();
    }
    if (t < 896) partials[t] = sd[t] - v;   // exclusive
}

__global__ __launch_bounds__(512) void scan3_kernel(int* __restrict__ hist_offs, const int* __restrict__ partials,
                                                    int* __restrict__ cursor) {
    __shared__ int sd[512];
    int t = threadIdx.x;
    int i = blockIdx.x * 512 + t;
    int c = hist_offs[i];
    sd[t] = c;
    __syncthreads();
    for (int off = 1; off < 512; off <<= 1) {
        int u = (t >= off) ? sd[t - off] : 0;
        __syncthreads();
        sd[t] += u;
        __syncthreads();
    }
    int o = partials[blockIdx.x] + sd[t] - c;
    hist_offs[i] = o;
    cursor[i] = o;
}

// ---------- K6: fill elist (+ pack col*7+etype for split path) + re-zero S/Q ----------
__global__ __launch_bounds__(256) void fill_zero_kernel(const int* __restrict__ ei, const int* __restrict__ et,
                                                        int* __restrict__ cursor, int* __restrict__ elist,
                                                        float* __restrict__ S, float* __restrict__ Q, int pack) {
    int bid = blockIdx.x;
    if (bid < 1792) {
        int e = bid * 256 + threadIdx.x;
        int t = et[e];
        int s = ei[e] * 7 + t;
        int p = atomicAdd(&cursor[s], 1);
        int c = ei[E_EDGES + e];   // col
        if (p >= 0 && p < E_EDGES) elist[p] = pack ? (c * 7 + t) : c;
    } else {
        int i = (bid - 1792) * 256 + threadIdx.x;   // 8*256 == 2048 exactly
        S[i] = 0.f; Q[i] = 0.f;
    }
}

// ---------- z-GEMM: z[m][t*256+c] = (y[m]|onehot) . W_t   (dense, barrier-free K-loop) ----------
// 256 thr, 4 waves x (64m x 64n). A panel (64 x 296 u16, 37.9 KB) staged by
// global_load_lds (linear copy of contiguous y rows; stride 148 dwords -> 2-way
// banks on frag reads = free). ONE barrier after stage, then 9 unrolled K=32
// phases of {4 ds_read_b128, 16 MFMA} with B (1 MB, L2-resident) in a 2-deep
// register ring. Epilogue bounces acc through LDS for 16B coalesced z stores.
__global__ __launch_bounds__(256) void zgemm_kernel(const u16* __restrict__ y,
                                                    const u16* __restrict__ W,
                                                    u16* __restrict__ z) {
    __shared__ __align__(16) u16 As[64 * YSTR];
    int tid = threadIdx.x;
    int lane = tid & 63;
    int wn = tid >> 6;
    int lm = lane & 15, lq = lane >> 4;
    int bid = blockIdx.x;
    int wg = (bid & 7) * 896 + (bid >> 3);     // XCD swizzle (7168 % 8 == 0)
    int mblk = wg / 7, nblk = wg % 7;          // 7 n-blocks of one m-panel adjacent
    int m0 = mblk * 64;

    const u16* yg = y + (size_t)m0 * YSTR;
#pragma unroll
    for (int i = 0; i < 9; i++) {              // 64*296 u16 = 2368 x 16B units
        int u = i * 256 + tid;
        gload16(yg + (size_t)u * 8, &As[u * 8]);
    }
    if (tid < 64) {
        int u = 2304 + tid;
        gload16(yg + (size_t)u * 8, &As[u * 8]);
    }

    f32x4 acc[4][4];
    f32x4 zz = {0.f, 0.f, 0.f, 0.f};
#pragma unroll
    for (int i = 0; i < 4; i++)
#pragma unroll
        for (int j = 0; j < 4; j++) acc[i][j] = zz;
    const u16* bp = W + (size_t)(nblk * 256 + wn * 64 + lm) * 288 + lq * 8;

    __syncthreads();                           // drains global_load_lds (vmcnt 0)

    bf16x8 bc[4], bn[4];
#pragma unroll
    for (int j = 0; j < 4; j++) bc[j] = *(const bf16x8*)&bp[j * 4608];

#pragma unroll
    for (int ph = 0; ph < 9; ph++) {
        bf16x8 a[4];
#pragma unroll
        for (int i = 0; i < 4; i++)
            a[i] = *(const bf16x8*)&As[(i * 16 + lm) * YSTR + ph * 32 + lq * 8];
        if (ph < 8) {
#pragma unroll
            for (int j = 0; j < 4; j++) bn[j] = *(const bf16x8*)&bp[j * 4608 + (ph + 1) * 32];
        }
        __builtin_amdgcn_s_setprio(1);
#pragma unroll
        for (int i = 0; i < 4; i++)
#pragma unroll
            for (int j = 0; j < 4; j++)
                acc[i][j] = __builtin_amdgcn_mfma_f32_16x16x32_bf16(a[i], bc[j], acc[i][j], 0, 0, 0);
        __builtin_amdgcn_s_setprio(0);
        if (ph < 8) {
#pragma unroll
            for (int j = 0; j < 4; j++) bc[j] = bn[j];
        }
    }

    // epilogue: acc -> bf16 -> LDS -> coalesced 16B global stores
    __syncthreads();
#pragma unroll
    for (int i = 0; i < 4; i++)
#pragma unroll
        for (int r = 0; r < 4; r++) {
            int row = i * 16 + lq * 4 + r;
#pragma unroll
            for (int j = 0; j < 4; j++)
                As[row * 256 + wn * 64 + j * 16 + lm] = f2bf(acc[i][j][r]);
        }
    __syncthreads();
#pragma unroll
    for (int k = 0; k < 8; k++) {              // 64*256 u16 = 2048 x 16B units
        int u = k * 256 + tid;
        int ru = u >> 5, cu = u & 31;
        *(u16x8*)&z[((size_t)m0 + ru) * ZN + nblk * 256 + cu * 8] =
            *(const u16x8*)&As[ru * 256 + cu * 8];
    }
}

// ---------- scatter-sum: out[r] = sum_{edges of r} z[col*7+t] + (emb | x skip) ----------
// 8 rows x 32 oct-threads per block; per edge one coalesced 512B z-row read.
// Row r's edges are contiguous: elist[offs[r*7] .. cursor[r*7+6]).
__global__ __launch_bounds__(256) void scatter_kernel(const u16* __restrict__ z,
        const int* __restrict__ offs, const int* __restrict__ cursor,
        const int* __restrict__ elist, const int* __restrict__ batch_id,
        const float* __restrict__ embout, const float* __restrict__ xres,
        float* __restrict__ out, int mode) {
    int tid = threadIdx.x;
    int r = blockIdx.x * 8 + (tid >> 5);
    int oct = tid & 31;
    int st = offs[r * 7];
    int en = cursor[r * 7 + 6];
    float a0[8], a1[8];
#pragma unroll
    for (int j = 0; j < 8; j++) { a0[j] = 0.f; a1[j] = 0.f; }
    int e = st;
    for (; e + 2 <= en; e += 2) {
        int i0 = elist[e], i1 = elist[e + 1];
        u16x8 v0 = *(const u16x8*)&z[(size_t)i0 * 256 + oct * 8];
        u16x8 v1 = *(const u16x8*)&z[(size_t)i1 * 256 + oct * 8];
#pragma unroll
        for (int j = 0; j < 8; j++) { a0[j] += bf2f(v0[j]); a1[j] += bf2f(v1[j]); }
    }
    if (e < en) {
        u16x8 v0 = *(const u16x8*)&z[(size_t)elist[e] * 256 + oct * 8];
#pragma unroll
        for (int j = 0; j < 8; j++) a0[j] += bf2f(v0[j]);
    }
    const float* ap = (mode == 0) ? &embout[batch_id[r] * 256 + oct * 8]
                                  : &xres[(size_t)r * 256 + oct * 8];
    f32x4 o0, o1;
#pragma unroll
    for (int j = 0; j < 4; j++) o0[j] = a0[j] + a1[j] + ap[j];
#pragma unroll
    for (int j = 0; j < 4; j++) o1[j] = a0[4 + j] + a1[4 + j] + ap[4 + j];
    *(f32x4*)&out[(size_t)r * 256 + oct * 8] = o0;
    *(f32x4*)&out[(size_t)r * 256 + oct * 8 + 4] = o1;
}

// ---------- FALLBACK: round-3 fused aggregate+GEMM (y stride 296), used if ws too small ----------
__global__ __launch_bounds__(512) void gemm_fused_kernel(
    const u16* __restrict__ y, const u16* __restrict__ Bt,
    const int* __restrict__ offs, const int* __restrict__ cursor,
    const int* __restrict__ elist, const int* __restrict__ node_type,
    const int* __restrict__ batch_id, const float* __restrict__ embout,
    const float* __restrict__ xres, float* __restrict__ out, int mode)
{
    __shared__ __align__(16) u16 As[2][64 * 64];
    int tid = threadIdx.x;
    int lane = tid & 63;
    int wn = tid >> 6;
    int lm = lane & 15, lq = lane >> 4;
    int m0 = blockIdx.x * 64;
    int ar = tid >> 3;
    int tq = tid & 7;

    f32x4 acc[4][2];
    f32x4 zz = {0.f, 0.f, 0.f, 0.f};
#pragma unroll
    for (int i = 0; i < 4; i++)
#pragma unroll
        for (int j = 0; j < 2; j++) acc[i][j] = zz;

    const u16* btp0 = Bt + (size_t)(wn * 32 + lm) * GK + lq * 8;
    const u16* btp1 = btp0 + (size_t)16 * GK;

    int sbase = (m0 + ar) * 7;
    int st = offs[sbase], en = cursor[sbase];
    int col[4];
#pragma unroll
    for (int u = 0; u < 4; u++) col[u] = (st + u < en) ? elist[st + u] : -1;
    u16x8 gv[4];
#pragma unroll
    for (int u = 0; u < 4; u++)
        if (col[u] >= 0) gv[u] = *(const u16x8*)&y[(size_t)col[u] * YSTR + tq * 8];
    bf16x8 bcur[2][2];
#pragma unroll
    for (int k = 0; k < 2; k++) {
        bcur[k][0] = *(const bf16x8*)&btp0[k * 32];
        bcur[k][1] = *(const bf16x8*)&btp1[k * 32];
    }
    bf16x8 boh[2];
    int stn = 0, enn = 0;
    int coln[4] = {-1, -1, -1, -1};
    int nt4[4] = {-1, -1, -1, -1};
    int buf = 0;

    for (int t = 0; t < 7; t++) {
#pragma unroll
        for (int sc = 0; sc < 4; sc++) {
            float f[8];
#pragma unroll
            for (int j = 0; j < 8; j++) f[j] = 0.f;
#pragma unroll
            for (int u = 0; u < 4; u++)
                if (col[u] >= 0) {
#pragma unroll
                    for (int j = 0; j < 8; j++) f[j] += bf2f(gv[u][j]);
                }
            if (en - st > 4) {
                for (int e = st + 4; e < en; e++) {
                    u16x8 v = *(const u16x8*)&y[(size_t)elist[e] * YSTR + sc * 64 + tq * 8];
#pragma unroll
                    for (int j = 0; j < 8; j++) f[j] += bf2f(v[j]);
                }
            }
            {
                u16x8 w8;
#pragma unroll
                for (int j = 0; j < 8; j++) w8[j] = f2bf(f[j]);
                *(u16x8*)&As[buf][ar * 64 + ((tq ^ (ar & 7)) * 8)] = w8;
            }
            __syncthreads();
            bf16x8 a[2][4];
#pragma unroll
            for (int k = 0; k < 2; k++)
#pragma unroll
                for (int i = 0; i < 4; i++) {
                    int row = i * 16 + lm;
                    a[k][i] = *(const bf16x8*)&As[buf][row * 64 + (((k * 4 + lq) ^ (row & 7)) * 8)];
                }
            bf16x8 bn00, bn01, bn10, bn11;
            if (sc < 3) {
                int cb = (sc + 1) * 64 + tq * 8;
#pragma unroll
                for (int u = 0; u < 4; u++)
                    if (col[u] >= 0) gv[u] = *(const u16x8*)&y[(size_t)col[u] * YSTR + cb];
                int kb = t * TSTRIDE + (sc + 1) * 64;
                bn00 = *(const bf16x8*)&btp0[kb];
                bn01 = *(const bf16x8*)&btp1[kb];
                bn10 = *(const bf16x8*)&btp0[kb + 32];
                bn11 = *(const bf16x8*)&btp1[kb + 32];
                if (sc == 0 && t < 6) { stn = offs[sbase + t + 1]; enn = cursor[sbase + t + 1]; }
                if (sc == 1 && t < 6) {
#pragma unroll
                    for (int u = 0; u < 4; u++) coln[u] = (stn + u < enn) ? elist[stn + u] : -1;
                }
                if (sc == 2 && tq == 0) {
#pragma unroll
                    for (int u = 0; u < 4; u++) nt4[u] = (col[u] >= 0) ? node_type[col[u]] : -1;
                }
            } else {
                int kb = t * TSTRIDE + 256;
                boh[0] = *(const bf16x8*)&btp0[kb];
                boh[1] = *(const bf16x8*)&btp1[kb];
                if (t < 6) {
#pragma unroll
                    for (int u = 0; u < 4; u++)
                        if (coln[u] >= 0) gv[u] = *(const u16x8*)&y[(size_t)coln[u] * YSTR + tq * 8];
                }
            }
            __builtin_amdgcn_s_setprio(1);
#pragma unroll
            for (int k = 0; k < 2; k++)
#pragma unroll
                for (int i = 0; i < 4; i++) {
                    acc[i][0] = __builtin_amdgcn_mfma_f32_16x16x32_bf16(a[k][i], bcur[k][0], acc[i][0], 0, 0, 0);
                    acc[i][1] = __builtin_amdgcn_mfma_f32_16x16x32_bf16(a[k][i], bcur[k][1], acc[i][1], 0, 0, 0);
                }
            __builtin_amdgcn_s_setprio(0);
            if (sc < 3) { bcur[0][0] = bn00; bcur[0][1] = bn01; bcur[1][0] = bn10; bcur[1][1] = bn11; }
            buf ^= 1;
        }
        {
            u16x8 w8;
#pragma unroll
            for (int j = 0; j < 8; j++) w8[j] = 0;
            if (tq == 0) {
                float oh[7];
#pragma unroll
                for (int j = 0; j < 7; j++)
                    oh[j] = (nt4[0] == j ? 1.f : 0.f) + (nt4[1] == j ? 1.f : 0.f)
                          + (nt4[2] == j ? 1.f : 0.f) + (nt4[3] == j ? 1.f : 0.f);
                if (en - st > 4) {
                    for (int e = st + 4; e < en; e++) {
                        int nt = node_type[elist[e]];
#pragma unroll
                        for (int j = 0; j < 7; j++) oh[j] += (nt == j) ? 1.f : 0.f;
                    }
                }
#pragma unroll
                for (int j = 0; j < 7; j++) w8[j] = f2bf(oh[j]);
            }
            *(u16x8*)&As[buf][ar * 64 + ((tq ^ (ar & 7)) * 8)] = w8;
            __syncthreads();
            bf16x8 a[4];
#pragma unroll
            for (int i = 0; i < 4; i++) {
                int row = i * 16 + lm;
                a[i] = *(const bf16x8*)&As[buf][row * 64 + ((lq ^ (row & 7)) * 8)];
            }
            if (t < 6) {
                int kb = (t + 1) * TSTRIDE;
                bcur[0][0] = *(const bf16x8*)&btp0[kb];
                bcur[0][1] = *(const bf16x8*)&btp1[kb];
                bcur[1][0] = *(const bf16x8*)&btp0[kb + 32];
                bcur[1][1] = *(const bf16x8*)&btp1[kb + 32];
            }
            __builtin_amdgcn_s_setprio(1);
#pragma unroll
            for (int i = 0; i < 4; i++) {
                acc[i][0] = __builtin_amdgcn_mfma_f32_16x16x32_bf16(a[i], boh[0], acc[i][0], 0, 0, 0);
                acc[i][1] = __builtin_amdgcn_mfma_f32_16x16x32_bf16(a[i], boh[1], acc[i][1], 0, 0, 0);
            }
            __builtin_amdgcn_s_setprio(0);
            st = stn; en = enn;
#pragma unroll
            for (int u = 0; u < 4; u++) col[u] = coln[u];
            buf ^= 1;
        }
    }

#pragma unroll
    for (int i = 0; i < 4; i++) {
#pragma unroll
        for (int r = 0; r < 4; r++) {
            size_t m = (size_t)m0 + i * 16 + lq * 4 + r;
            float addv[2];
            if (mode == 0) {
                int b = batch_id[m];
#pragma unroll
                for (int j = 0; j < 2; j++) addv[j] = embout[b * 256 + wn * 32 + j * 16 + lm];
            } else {
#pragma unroll
                for (int j = 0; j < 2; j++) addv[j] = xres[m * 256 + wn * 32 + j * 16 + lm];
            }
#pragma unroll
            for (int j = 0; j < 2; j++) {
                int n = wn * 32 + j * 16 + lm;
                out[m * 256 + n] = acc[i][j][r] + addv[j];
            }
        }
    }
}

// ---------- host ----------
extern "C" void kernel_launch(void* const* d_in, const int* in_sizes, int n_in,
                              void* d_out, int out_size, void* d_ws, size_t ws_size,
                              hipStream_t stream) {
    const float* x    = (const float*)d_in[0];
    const float* emb  = (const float*)d_in[1];
    const int* bid    = (const int*)d_in[2];
    const int* ei     = (const int*)d_in[3];
    const int* et     = (const int*)d_in[4];
    const int* ntp    = (const int*)d_in[5];
    const float* gn1w = (const float*)d_in[6];
    const float* gn1b = (const float*)d_in[7];
    const float* w1   = (const float*)d_in[8];
    const float* embw = (const float*)d_in[9];
    const float* embb = (const float*)d_in[10];
    const float* gn2w = (const float*)d_in[11];
    const float* gn2b = (const float*)d_in[12];
    const float* w2   = (const float*)d_in[13];
    float* out = (float*)d_out;

    char* p = (char*)d_ws;
    size_t off = 0;
    auto nxt = [&](size_t bytes) -> void* {
        void* r = p + off;
        off += (bytes + 255) & ~(size_t)255;
        return r;
    };
    u16*   y       = (u16*)nxt((size_t)N_NODES * YSTR * 2);    // 38.8 MB
    u16*   Wt1     = (u16*)nxt((size_t)ZN * 288 * 2);          // 1.03 MB (= 256*GK*2)
    u16*   Wt2     = (u16*)nxt((size_t)ZN * 288 * 2);
    float* embout  = (float*)nxt(8 * 256 * 4);
    float* S       = (float*)nxt(2048 * 4);
    float* Q       = (float*)nxt(2048 * 4);
    int*   cnt     = (int*)nxt(8 * 4);
    int*   offs    = (int*)nxt((size_t)NSEG * 4);
    int*   cursor  = (int*)nxt((size_t)NSEG * 4);
    int*   parts   = (int*)nxt(1024 * 4);
    int*   elist   = (int*)nxt((size_t)E_EDGES * 4);
    u16*   z       = (u16*)nxt((size_t)N_NODES * ZN * 2);      // 235 MB (split path only)
    float* h2      = out;   // d_out doubles as h2 (dead before final write)
    int split = (off <= ws_size) ? 1 : 0;
    (void)in_sizes; (void)n_in; (void)out_size;

    hipMemsetAsync(offs, 0, (size_t)NSEG * 4, stream);
    hipMemsetAsync(S, 0, 16416, stream);                       // S + Q + cnt
    front_kernel<<<2289, 256, 0, stream>>>(bid, cnt, w1, w2, Wt1, Wt2,
                                           emb, embw, embb, embout, x, S, Q, split);
    hist_norm_kernel<<<9984, 256, 0, stream>>>(ei, et, offs, x, bid, S, Q, cnt, gn1w, gn1b, ntp, y);
    scan1_kernel<<<896, 512, 0, stream>>>(offs, parts);
    scan2_kernel<<<1, 1024, 0, stream>>>(parts);
    scan3_kernel<<<896, 512, 0, stream>>>(offs, parts, cursor);
    fill_zero_kernel<<<1800, 256, 0, stream>>>(ei, et, cursor, elist, S, Q, split);

    if (split) {
        // conv1 = dense z-GEMM + gather-sum scatter
        zgemm_kernel<<<7168, 256, 0, stream>>>(y, Wt1, z);
        scatter_kernel<<<8192, 256, 0, stream>>>(z, offs, cursor, elist, bid, embout, x, h2, 0);
        stats_kernel<<<1024, 256, 0, stream>>>(h2, bid, S, Q);
        norm_kernel<<<8192, 256, 0, stream>>>(h2, bid, S, Q, cnt, gn2w, gn2b, ntp, y);
        zgemm_kernel<<<7168, 256, 0, stream>>>(y, Wt2, z);
        scatter_kernel<<<8192, 256, 0, stream>>>(z, offs, cursor, elist, bid, embout, x, out, 1);
    } else {
        gemm_fused_kernel<<<1024, 512, 0, stream>>>(y, Wt1, offs, cursor, elist, ntp, bid, embout, x, h2, 0);
        stats_kernel<<<1024, 256, 0, stream>>>(h2, bid, S, Q);
        norm_kernel<<<8192, 256, 0, stream>>>(h2, bid, S, Q, cnt, gn2w, gn2b, ntp, y);
        gemm_fused_kernel<<<1024, 512, 0, stream>>>(y, Wt2, offs, cursor, elist, ntp, bid, embout, x, out, 1);
    }
}

// Round 5
// 736.189 us; speedup vs baseline: 1.0256x; 1.0256x over previous
//
#include <hip/hip_runtime.h>
#include <math.h>

// ---------- Problem constants ----------
#define N_NODES 65536
#define B_GR    8
#define EMB_N   512
#define E_EDGES 458752     // N * 7
#define NSEG    458752     // N * 7 segments (row*7 + etype)
#define TSTRIDE 288        // per-type padded K (263 used: 256 feat + 7 onehot)
#define GK      2016       // 7 * 288
#define YSTR    296        // y row stride u16 (288 data + 8 pad)
#define EPS     1e-5f

typedef unsigned short u16;
typedef unsigned int   u32;
typedef __bf16 bf16x8 __attribute__((ext_vector_type(8)));
typedef float  f32x4  __attribute__((ext_vector_type(4)));
typedef u16    u16x8  __attribute__((ext_vector_type(8)));

__device__ __forceinline__ float bf2f(u16 u) {
    u32 x = ((u32)u) << 16; float f; __builtin_memcpy(&f, &x, 4); return f;
}
__device__ __forceinline__ u16 f2bf(float f) {
    u32 x; __builtin_memcpy(&x, &f, 4);
    u32 r = x + 0x7fffu + ((x >> 16) & 1u);
    return (u16)(r >> 16);
}

// ---------- shared device bodies ----------
__device__ __forceinline__ void stats_body(int nb, int tid, const float* __restrict__ xin,
                                           const int* __restrict__ batch_id,
                                           float* __restrict__ S, float* __restrict__ Q) {
    int c = tid;
    int n0 = nb * 64;
    float s = 0.f, q = 0.f;
    int bcur = batch_id[n0];
    for (int r = 0; r < 64; r++) {
        int n = n0 + r;
        int b = batch_id[n];
        if (b != bcur) {
            atomicAdd(&S[bcur * 256 + c], s);
            atomicAdd(&Q[bcur * 256 + c], q);
            s = 0.f; q = 0.f; bcur = b;
        }
        float v = xin[(size_t)n * 256 + c];
        s += v;
        q = fmaf(v, v, q);
    }
    atomicAdd(&S[bcur * 256 + c], s);
    atomicAdd(&Q[bcur * 256 + c], q);
}

// norm + affine + SiLU with inline group-stat finalize; writes y stride 296:
// cols 0..255 = silu(gn(x)); 256..262 = onehot(node_type); 263..287 = 0.
__device__ __forceinline__ void norm_body(int nb, int tid, const float* __restrict__ xin,
                                          const int* __restrict__ batch_id,
                                          const float* __restrict__ S, const float* __restrict__ Q,
                                          const int* __restrict__ cnt,
                                          const float* __restrict__ w, const float* __restrict__ bias,
                                          const int* __restrict__ node_type,
                                          u16* __restrict__ yout) {
    __shared__ float smean[256], sistd[256];
    {
        int b = tid >> 5, g = tid & 31;
        float Sg = 0.f, Qg = 0.f;
#pragma unroll
        for (int k = 0; k < 8; k++) {
            Sg += S[b * 256 + g * 8 + k];
            Qg += Q[b * 256 + g * 8 + k];
        }
        float cnt8 = (float)cnt[b] * 8.f;
        float D = cnt8 + EPS;                  // matches reference: count*cpg + EPS
        float m = Sg / D;
        float var = (Qg - 2.f * m * Sg + cnt8 * m * m) / D;
        smean[tid] = m;
        sistd[tid] = rsqrtf(var + EPS);
    }
    __syncthreads();
    int n = nb * 8 + (tid >> 5);
    int g = tid & 31;
    int c0 = g * 8;
    int b = batch_id[n];
    float m = smean[b * 32 + g], is = sistd[b * 32 + g];
    u16x8 o;
#pragma unroll
    for (int k = 0; k < 8; k++) {
        float v = (xin[(size_t)n * 256 + c0 + k] - m) * is;
        v = v * w[c0 + k] + bias[c0 + k];
        v = v / (1.f + __expf(-v));
        o[k] = f2bf(v);
    }
    *(u16x8*)&yout[(size_t)n * YSTR + c0] = o;
    if (g < 4) {                    // append onehot + zero octets (cols 256..287)
        u16x8 oh;
#pragma unroll
        for (int k = 0; k < 8; k++) oh[k] = 0;
        if (g == 0) {
            int nt = node_type[n];
#pragma unroll
            for (int k = 0; k < 7; k++) oh[k] = (nt == k) ? (u16)0x3F80 : (u16)0;
        }
        *(u16x8*)&yout[(size_t)n * YSTR + 256 + g * 8] = oh;
    }
}

// ---------- K1: count + weight transpose + emb GEMM + stats1 (fused front) ----------
__global__ __launch_bounds__(256) void front_kernel(
    const int* __restrict__ batch_id, int* __restrict__ cnt,
    const float* __restrict__ w1, const float* __restrict__ w2,
    u16* __restrict__ Wt1, u16* __restrict__ Wt2,
    const float* __restrict__ emb, const float* __restrict__ embw,
    const float* __restrict__ embb, float* __restrict__ embout,
    const float* __restrict__ x, float* __restrict__ S, float* __restrict__ Q)
{
    int bid = blockIdx.x, tid = threadIdx.x;
    if (bid < 256) {
        int i = bid * 256 + tid;
        int b = batch_id[i];
#pragma unroll
        for (int bb = 0; bb < 8; bb++) {
            unsigned long long mm = __ballot(b == bb);
            if ((tid & 63) == 0 && mm) atomicAdd(&cnt[bb], (int)__popcll(mm));
        }
    } else if (bid < 1264) {
        // weight transpose+pad (f32 -> bf16), 32x32 LDS tiles, coalesced both sides
        int r = bid - 256;
        const float* Win = (r < 504) ? w1 : w2;
        u16* Wt = (r < 504) ? Wt1 : Wt2;
        r %= 504;
        int t  = r / 72;
        int r2 = r % 72;
        int cc0 = (r2 / 8) * 32;       // 9 c-tiles cover padded 0..287
        int n0  = (r2 % 8) * 32;
        __shared__ float tile[32][33];
        int cl = tid & 31, rh = tid >> 5;
#pragma unroll
        for (int rr = 0; rr < 4; rr++) {
            int c = cc0 + rh + rr * 8;
            float v = 0.f;
            if (c < 263) v = Win[(size_t)(t * 263 + c) * 256 + n0 + cl];
            tile[rh + rr * 8][cl] = v;
        }
        __syncthreads();
#pragma unroll
        for (int rr = 0; rr < 4; rr++) {
            int n = n0 + rh + rr * 8;
            Wt[(size_t)n * GK + t * TSTRIDE + cc0 + cl] = f2bf(tile[cl][rh + rr * 8]);
        }
    } else if (bid == 1264) {
        __shared__ float semb[B_GR * EMB_N];
        for (int i = tid; i < B_GR * EMB_N; i += 256) {
            float e = emb[i];
            semb[i] = e / (1.f + __expf(-e));
        }
        __syncthreads();
        float acc[8];
        float bb = embb[tid];
#pragma unroll
        for (int b = 0; b < 8; b++) acc[b] = bb;
        for (int k = 0; k < EMB_N; k++) {
            float wv = embw[k * 256 + tid];
#pragma unroll
            for (int b = 0; b < 8; b++) acc[b] += semb[b * EMB_N + k] * wv;
        }
#pragma unroll
        for (int b = 0; b < 8; b++) embout[b * 256 + tid] = acc[b];
    } else {
        stats_body(bid - 1265, tid, x, batch_id, S, Q);
    }
}

// ---------- K2: hist + norm1 (fused) ----------
__global__ __launch_bounds__(256) void hist_norm_kernel(
    const int* __restrict__ ei, const int* __restrict__ et, int* __restrict__ hist,
    const float* __restrict__ xin, const int* __restrict__ batch_id,
    const float* __restrict__ S, const float* __restrict__ Q, const int* __restrict__ cnt,
    const float* __restrict__ w, const float* __restrict__ bias,
    const int* __restrict__ node_type, u16* __restrict__ yout)
{
    int bid = blockIdx.x;
    if (bid < 1792) {
        int e = bid * 256 + threadIdx.x;   // 1792*256 == E_EDGES exactly
        int s = ei[e] * 7 + et[e];
        atomicAdd(&hist[s], 1);
    } else {
        norm_body(bid - 1792, threadIdx.x, xin, batch_id, S, Q, cnt, w, bias, node_type, yout);
    }
}

// ---------- standalone stats2 / norm2 ----------
__global__ __launch_bounds__(256) void stats_kernel(const float* __restrict__ xin,
                                                    const int* __restrict__ batch_id,
                                                    float* __restrict__ S, float* __restrict__ Q) {
    stats_body(blockIdx.x, threadIdx.x, xin, batch_id, S, Q);
}
__global__ __launch_bounds__(256) void norm_kernel(const float* __restrict__ xin,
                                                   const int* __restrict__ batch_id,
                                                   const float* __restrict__ S, const float* __restrict__ Q,
                                                   const int* __restrict__ cnt,
                                                   const float* __restrict__ w, const float* __restrict__ bias,
                                                   const int* __restrict__ node_type,
                                                   u16* __restrict__ yout) {
    norm_body(blockIdx.x, threadIdx.x, xin, batch_id, S, Q, cnt, w, bias, node_type, yout);
}

// ---------- CSR scans ----------
__global__ __launch_bounds__(512) void scan1_kernel(const int* __restrict__ hist, int* __restrict__ partials) {
    __shared__ int sd[512];
    int i = blockIdx.x * 512 + threadIdx.x;
    sd[threadIdx.x] = hist[i];
    __syncthreads();
    for (int off = 256; off > 0; off >>= 1) {
        if (threadIdx.x < off) sd[threadIdx.x] += sd[threadIdx.x + off];
        __syncthreads();
    }
    if (threadIdx.x == 0) partials[blockIdx.x] = sd[0];
}

__global__ __launch_bounds__(1024) void scan2_kernel(int* __restrict__ partials) {
    __shared__ int sd[1024];
    int t = threadIdx.x;
    int v = (t < 896) ? partials[t] : 0;
    sd[t] = v;
    __syncthreads();
    for (int off = 1; off < 1024; off <<= 1) {
        int u = (t >= off) ? sd[t - off] : 0;
        __syncthreads();
        sd[t] += u;
        __syncthreads();
    }
    if (t < 896) partials[t] = sd[t] - v;   // exclusive
}

__global__ __launch_bounds__(512) void scan3_kernel(int* __restrict__ hist_offs, const int* __restrict__ partials,
                                                    int* __restrict__ cursor) {
    __shared__ int sd[512];
    int t = threadIdx.x;
    int i = blockIdx.x * 512 + t;
    int c = hist_offs[i];
    sd[t] = c;
    __syncthreads();
    for (int off = 1; off < 512; off <<= 1) {
        int u = (t >= off) ? sd[t - off] : 0;
        __syncthreads();
        sd[t] += u;
        __syncthreads();
    }
    int o = partials[blockIdx.x] + sd[t] - c;
    hist_offs[i] = o;
    cursor[i] = o;
}

// ---------- K6: fill elist + re-zero S/Q for GN2 ----------
__global__ __launch_bounds__(256) void fill_zero_kernel(const int* __restrict__ ei, const int* __restrict__ et,
                                                        int* __restrict__ cursor, int* __restrict__ elist,
                                                        float* __restrict__ S, float* __restrict__ Q) {
    int bid = blockIdx.x;
    if (bid < 1792) {
        int e = bid * 256 + threadIdx.x;
        int s = ei[e] * 7 + et[e];
        int p = atomicAdd(&cursor[s], 1);
        if (p >= 0 && p < E_EDGES) elist[p] = ei[E_EDGES + e];   // col
    } else {
        int i = (bid - 1792) * 256 + threadIdx.x;   // 8*256 == 2048 exactly
        S[i] = 0.f; Q[i] = 0.f;
    }
}

// ---------- fused aggregate + MFMA GEMM: DISTANCE-2 gather prefetch ----------
// 512 thr, 8 waves x (64m x 32n). Per type: 5 phases (4 x 64ch + 1 x 32ch
// "onehot" phase that is now a PLAIN GATHER of y cols 256..287 -- y carries
// onehot inline, so no node_type logic in the hot loop). At phase p the
// y-gathers for phase p+2 are issued (two gv sets, ping-ponged by register
// swap -- SSA-renamed, all indices compile-time). Cross-type: offs@sc0,
// elist cols@sc1, (t+1,sc0) gathers@sc3, (t+1,sc1)@sc4. Every gather has
// >=2 phases (~600-800 cyc) of cover vs ~500-600 cyc L3 latency.
// As[2][64x64] dbuf, XOR slot swizzle (conflict-free), ONE barrier/phase.
// B: 1-phase register ring from L2-resident Wt (1 MB).
// NO __launch_bounds__ reg cap (round-2 spill lesson); target <=128 VGPR
// to keep 2 blocks/CU (watch VGPR_Count + WRITE_SIZE==65536).
// mode 0: out = acc + embout[batch_id[m]][n]; mode 1: out = acc + x[m][n]
__global__ __launch_bounds__(512) void gemm_fused_kernel(
    const u16* __restrict__ y, const u16* __restrict__ Bt,
    const int* __restrict__ offs, const int* __restrict__ cursor,
    const int* __restrict__ elist,
    const int* __restrict__ batch_id, const float* __restrict__ embout,
    const float* __restrict__ xres, float* __restrict__ out, int mode)
{
    __shared__ __align__(16) u16 As[2][64 * 64];   // 16 KB double-buffered
    int tid = threadIdx.x;
    int lane = tid & 63;
    int wn = tid >> 6;                 // 8 waves, each 64(m) x 32(n)
    int lm = lane & 15, lq = lane >> 4;
    int m0 = blockIdx.x * 64;
    int ar = tid >> 3;                 // gather row 0..63
    int tq = tid & 7;                  // channel octet 0..7
    int oq = tq & 3;                   // octet within 32-ch phase

    f32x4 acc[4][2];
    f32x4 zz = {0.f, 0.f, 0.f, 0.f};
#pragma unroll
    for (int i = 0; i < 4; i++)
#pragma unroll
        for (int j = 0; j < 2; j++) acc[i][j] = zz;

    const u16* btp0 = Bt + (size_t)(wn * 32 + lm) * GK + lq * 8;
    const u16* btp1 = btp0 + (size_t)16 * GK;

    int sbase = (m0 + ar) * 7;

    // ---- prologue: type-0 CSR + gathers for phases (0,0) and (0,1) + B ----
    int st = offs[sbase], en = cursor[sbase];
    int col[4];
#pragma unroll
    for (int u = 0; u < 4; u++) col[u] = (st + u < en) ? elist[st + u] : -1;
    u16x8 gvA[4], gvB[4];
#pragma unroll
    for (int u = 0; u < 4; u++)
        if (col[u] >= 0) gvA[u] = *(const u16x8*)&y[(size_t)col[u] * YSTR + tq * 8];
#pragma unroll
    for (int u = 0; u < 4; u++)
        if (col[u] >= 0) gvB[u] = *(const u16x8*)&y[(size_t)col[u] * YSTR + 64 + tq * 8];

    bf16x8 bcur[2][2];
    bcur[0][0] = *(const bf16x8*)&btp0[0];
    bcur[0][1] = *(const bf16x8*)&btp1[0];
    bcur[1][0] = *(const bf16x8*)&btp0[32];
    bcur[1][1] = *(const bf16x8*)&btp1[32];

    int nst = 0, nen = 0, ncol[4] = {-1, -1, -1, -1};
    int buf = 0;

    for (int t = 0; t < 7; t++) {
#pragma unroll
        for (int sc = 0; sc < 5; sc++) {
            // ---- fold gvA (issued 2 phases ago) -> As[buf] ----
            float f[8];
#pragma unroll
            for (int j = 0; j < 8; j++) f[j] = 0.f;
#pragma unroll
            for (int u = 0; u < 4; u++)
                if (col[u] >= 0) {
#pragma unroll
                    for (int j = 0; j < 8; j++) f[j] += bf2f(gvA[u][j]);
                }
            if (en - st > 4) {          // rare overflow (0.37% of segments)
                int cb = (sc == 4) ? (256 + oq * 8) : (sc * 64 + tq * 8);
                for (int e = st + 4; e < en; e++) {
                    u16x8 v = *(const u16x8*)&y[(size_t)elist[e] * YSTR + cb];
#pragma unroll
                    for (int j = 0; j < 8; j++) f[j] += bf2f(v[j]);
                }
            }
            {
                u16x8 w8;
#pragma unroll
                for (int j = 0; j < 8; j++) w8[j] = f2bf(f[j]);
                int slot = (sc == 4) ? (oq ^ (ar & 7)) : (tq ^ (ar & 7));
                *(u16x8*)&As[buf][ar * 64 + slot * 8] = w8;   // sc4: tq,tq^4 dup same value
            }
            __syncthreads();
            // ---- A fragments ----
            bf16x8 a0[4], a1[4];
#pragma unroll
            for (int i = 0; i < 4; i++) {
                int row = i * 16 + lm;
                a0[i] = *(const bf16x8*)&As[buf][row * 64 + ((lq ^ (row & 7)) * 8)];
                if (sc < 4)
                    a1[i] = *(const bf16x8*)&As[buf][row * 64 + (((4 + lq) ^ (row & 7)) * 8)];
            }
            // ---- issue phase+2 gathers into gvA + B prefetch + CSR pipeline ----
            bf16x8 bn00, bn01, bn10, bn11;
            if (sc == 0) {
                int cb = 128 + tq * 8;
#pragma unroll
                for (int u = 0; u < 4; u++)
                    if (col[u] >= 0) gvA[u] = *(const u16x8*)&y[(size_t)col[u] * YSTR + cb];
                if (t < 6) { nst = offs[sbase + t + 1]; nen = cursor[sbase + t + 1]; }
                int kb = t * TSTRIDE + 64;
                bn00 = *(const bf16x8*)&btp0[kb];      bn01 = *(const bf16x8*)&btp1[kb];
                bn10 = *(const bf16x8*)&btp0[kb + 32]; bn11 = *(const bf16x8*)&btp1[kb + 32];
            } else if (sc == 1) {
                int cb = 192 + tq * 8;
#pragma unroll
                for (int u = 0; u < 4; u++)
                    if (col[u] >= 0) gvA[u] = *(const u16x8*)&y[(size_t)col[u] * YSTR + cb];
                if (t < 6) {
#pragma unroll
                    for (int u = 0; u < 4; u++) ncol[u] = (nst + u < nen) ? elist[nst + u] : -1;
                }
                int kb = t * TSTRIDE + 128;
                bn00 = *(const bf16x8*)&btp0[kb];      bn01 = *(const bf16x8*)&btp1[kb];
                bn10 = *(const bf16x8*)&btp0[kb + 32]; bn11 = *(const bf16x8*)&btp1[kb + 32];
            } else if (sc == 2) {
                int cb = 256 + oq * 8;
#pragma unroll
                for (int u = 0; u < 4; u++)
                    if (col[u] >= 0) gvA[u] = *(const u16x8*)&y[(size_t)col[u] * YSTR + cb];
                int kb = t * TSTRIDE + 192;
                bn00 = *(const bf16x8*)&btp0[kb];      bn01 = *(const bf16x8*)&btp1[kb];
                bn10 = *(const bf16x8*)&btp0[kb + 32]; bn11 = *(const bf16x8*)&btp1[kb + 32];
            } else if (sc == 3) {
                if (t < 6) {
                    int cb = tq * 8;
#pragma unroll
                    for (int u = 0; u < 4; u++)
                        if (ncol[u] >= 0) gvA[u] = *(const u16x8*)&y[(size_t)ncol[u] * YSTR + cb];
                }
                int kb = t * TSTRIDE + 256;            // next phase (sc4) is 32-wide
                bn00 = *(const bf16x8*)&btp0[kb];      bn01 = *(const bf16x8*)&btp1[kb];
            } else {  // sc == 4
                if (t < 6) {
                    int cb = 64 + tq * 8;
#pragma unroll
                    for (int u = 0; u < 4; u++)
                        if (ncol[u] >= 0) gvA[u] = *(const u16x8*)&y[(size_t)ncol[u] * YSTR + cb];
                    int kb = (t + 1) * TSTRIDE;        // next type, sc0 (64-wide)
                    bn00 = *(const bf16x8*)&btp0[kb];      bn01 = *(const bf16x8*)&btp1[kb];
                    bn10 = *(const bf16x8*)&btp0[kb + 32]; bn11 = *(const bf16x8*)&btp1[kb + 32];
                }
            }
            // ---- MFMA ----
            __builtin_amdgcn_s_setprio(1);
#pragma unroll
            for (int i = 0; i < 4; i++) {
                acc[i][0] = __builtin_amdgcn_mfma_f32_16x16x32_bf16(a0[i], bcur[0][0], acc[i][0], 0, 0, 0);
                acc[i][1] = __builtin_amdgcn_mfma_f32_16x16x32_bf16(a0[i], bcur[0][1], acc[i][1], 0, 0, 0);
            }
            if (sc < 4) {
#pragma unroll
                for (int i = 0; i < 4; i++) {
                    acc[i][0] = __builtin_amdgcn_mfma_f32_16x16x32_bf16(a1[i], bcur[1][0], acc[i][0], 0, 0, 0);
                    acc[i][1] = __builtin_amdgcn_mfma_f32_16x16x32_bf16(a1[i], bcur[1][1], acc[i][1], 0, 0, 0);
                }
            }
            __builtin_amdgcn_s_setprio(0);
            // ---- commit B ring ----
            if (sc == 3) {
                bcur[0][0] = bn00; bcur[0][1] = bn01;
            } else if (sc == 4) {
                if (t < 6) { bcur[0][0] = bn00; bcur[0][1] = bn01; bcur[1][0] = bn10; bcur[1][1] = bn11; }
            } else {
                bcur[0][0] = bn00; bcur[0][1] = bn01; bcur[1][0] = bn10; bcur[1][1] = bn11;
            }
            // ---- swap gather sets (pure SSA rename, no wait) ----
#pragma unroll
            for (int u = 0; u < 4; u++) { u16x8 tmp = gvA[u]; gvA[u] = gvB[u]; gvB[u] = tmp; }
            // ---- type rotation ----
            if (sc == 4) {
                st = nst; en = nen;
#pragma unroll
                for (int u = 0; u < 4; u++) col[u] = ncol[u];
            }
            buf ^= 1;
        }
    }

    // ---- epilogue ----
#pragma unroll
    for (int i = 0; i < 4; i++) {
#pragma unroll
        for (int r = 0; r < 4; r++) {
            size_t m = (size_t)m0 + i * 16 + lq * 4 + r;
            float addv[2];
            if (mode == 0) {
                int b = batch_id[m];
#pragma unroll
                for (int j = 0; j < 2; j++) addv[j] = embout[b * 256 + wn * 32 + j * 16 + lm];
            } else {
#pragma unroll
                for (int j = 0; j < 2; j++) addv[j] = xres[m * 256 + wn * 32 + j * 16 + lm];
            }
#pragma unroll
            for (int j = 0; j < 2; j++) {
                int n = wn * 32 + j * 16 + lm;
                out[m * 256 + n] = acc[i][j][r] + addv[j];
            }
        }
    }
}

// ---------- host ----------
extern "C" void kernel_launch(void* const* d_in, const int* in_sizes, int n_in,
                              void* d_out, int out_size, void* d_ws, size_t ws_size,
                              hipStream_t stream) {
    const float* x    = (const float*)d_in[0];
    const float* emb  = (const float*)d_in[1];
    const int* bid    = (const int*)d_in[2];
    const int* ei     = (const int*)d_in[3];
    const int* et     = (const int*)d_in[4];
    const int* ntp    = (const int*)d_in[5];
    const float* gn1w = (const float*)d_in[6];
    const float* gn1b = (const float*)d_in[7];
    const float* w1   = (const float*)d_in[8];
    const float* embw = (const float*)d_in[9];
    const float* embb = (const float*)d_in[10];
    const float* gn2w = (const float*)d_in[11];
    const float* gn2b = (const float*)d_in[12];
    const float* w2   = (const float*)d_in[13];
    float* out = (float*)d_out;

    char* p = (char*)d_ws;
    size_t off = 0;
    auto nxt = [&](size_t bytes) -> void* {
        void* r = p + off;
        off += (bytes + 255) & ~(size_t)255;
        return r;
    };
    u16*   y       = (u16*)nxt((size_t)N_NODES * YSTR * 2);    // 38.8 MB
    u16*   Wt1     = (u16*)nxt((size_t)256 * GK * 2);          // 1.03 MB
    u16*   Wt2     = (u16*)nxt((size_t)256 * GK * 2);
    float* embout  = (float*)nxt(8 * 256 * 4);
    float* S       = (float*)nxt(2048 * 4);
    float* Q       = (float*)nxt(2048 * 4);
    int*   cnt     = (int*)nxt(8 * 4);
    int*   offs    = (int*)nxt((size_t)NSEG * 4);              // hist, then offsets in place
    int*   cursor  = (int*)nxt((size_t)NSEG * 4);
    int*   parts   = (int*)nxt(1024 * 4);
    int*   elist   = (int*)nxt((size_t)E_EDGES * 4);
    float* h2      = out;   // d_out doubles as h2 (dead before final write)
    (void)ws_size; (void)in_sizes; (void)n_in; (void)out_size;

    hipMemsetAsync(offs, 0, (size_t)NSEG * 4, stream);
    hipMemsetAsync(S, 0, 16416, stream);                       // S + Q + cnt
    front_kernel<<<2289, 256, 0, stream>>>(bid, cnt, w1, w2, Wt1, Wt2,
                                           emb, embw, embb, embout, x, S, Q);
    hist_norm_kernel<<<9984, 256, 0, stream>>>(ei, et, offs, x, bid, S, Q, cnt, gn1w, gn1b, ntp, y);
    scan1_kernel<<<896, 512, 0, stream>>>(offs, parts);
    scan2_kernel<<<1, 1024, 0, stream>>>(parts);
    scan3_kernel<<<896, 512, 0, stream>>>(offs, parts, cursor);
    fill_zero_kernel<<<1800, 256, 0, stream>>>(ei, et, cursor, elist, S, Q);
    // conv1: fused aggregate+GEMM(+emb) -> h2 (in d_out)
    gemm_fused_kernel<<<1024, 512, 0, stream>>>(y, Wt1, offs, cursor, elist, bid, embout, x, h2, 0);
    stats_kernel<<<1024, 256, 0, stream>>>(h2, bid, S, Q);
    norm_kernel<<<8192, 256, 0, stream>>>(h2, bid, S, Q, cnt, gn2w, gn2b, ntp, y);
    // conv2: fused aggregate+GEMM(+x skip) -> out
    gemm_fused_kernel<<<1024, 512, 0, stream>>>(y, Wt2, offs, cursor, elist, bid, embout, x, out, 1);
}